// Round 14
// baseline (329.243 us; speedup 1.0000x reference)
//
#include <hip/hip_runtime.h>

typedef unsigned short u16;
typedef unsigned int u32;
typedef short short8 __attribute__((ext_vector_type(8)));
typedef float f32x4 __attribute__((ext_vector_type(4)));

#define NB   512
#define NPG  211
#define NOBJ 10
#define NVAL 200
#define NE   420
#define NN   (NB * NPG)

__device__ __forceinline__ float bf2f(u16 u){
  union { unsigned i; float f; } v; v.i = ((unsigned)u) << 16; return v.f;
}
__device__ __forceinline__ u16 f2bf(float f){
  union { float f; unsigned i; } v; v.f = f;
  return (u16)((v.i + 0x7FFFu + ((v.i >> 16) & 1u)) >> 16);
}
__device__ __forceinline__ float lo_bf(u32 u){ union{u32 i;float f;}v; v.i=u<<16; return v.f; }
__device__ __forceinline__ float hi_bf(u32 u){ union{u32 i;float f;}v; v.i=u&0xffff0000u; return v.f; }
__device__ __forceinline__ u32 pack_bf(float a, float b){ return (u32)f2bf(a) | ((u32)f2bf(b)<<16); }
__device__ __forceinline__ float lrelu(float s){ return s > 0.f ? s : 0.2f * s; }
__device__ __forceinline__ short8 pack8(ushort4 a, ushort4 b){
  short8 v;
  v[0]=(short)a.x; v[1]=(short)a.y; v[2]=(short)a.z; v[3]=(short)a.w;
  v[4]=(short)b.x; v[5]=(short)b.y; v[6]=(short)b.z; v[7]=(short)b.w;
  return v;
}
// 16B-chunk swizzled element index for MFMA LDS tiles.
__device__ __forceinline__ int s16(int r, int c){
  return (r << 7) + ((((c >> 3) ^ (r & 15)) << 3) | (c & 7));
}

#define AS_GLOBAL(p) ((const __attribute__((address_space(1))) void*)((const void*)(p)))
#define AS_LDS(p)    ((__attribute__((address_space(3))) void*)((void*)(p)))

// ---------------- prep (fused): W1t, W2t transpose + wms/wmd ----------------
__global__ __launch_bounds__(256) void k_prep(const float* __restrict__ W1, const float* __restrict__ W2,
                                              const float* __restrict__ as2, const float* __restrict__ ad2,
                                              u16* __restrict__ W1t, u16* __restrict__ W2t,
                                              float* __restrict__ wms, float* __restrict__ wmd){
  int gid = blockIdx.x * 256 + threadIdx.x;      // 324 blocks -> 82944
  if (gid < 16384){
    int k = gid >> 7, n = gid & 127;
    W1t[n * 128 + k] = f2bf(W1[k * 128 + n]);
  } else if (gid < 81920){
    int t = gid - 16384;
    int n = t >> 9, kk = t & 511;
    int h = kk >> 7, c = kk & 127;
    W2t[n * 512 + kk] = f2bf(W2[c * 512 + h * 128 + n]);
  } else {
    int t = gid - 81920;                          // 0..1023
    int which = t >> 9, hk = t & 511;
    int h = hk >> 7, k = hk & 127;
    const float* av = which ? ad2 : as2;
    float s = 0.f;
    for (int j = 0; j < 128; ++j)
      s += W2[k * 512 + h * 128 + j] * av[h * 128 + j];
    (which ? wmd : wms)[hk] = s;
  }
}

// ---- embed: x[n][c] bf16 (linear layout) ----
__global__ __launch_bounds__(256) void k_embed2(
    const float* __restrict__ head, const float* __restrict__ obj, const float* __restrict__ val,
    const float* __restrict__ Wh, const float* __restrict__ bh,
    const float* __restrict__ Wo, const float* __restrict__ bo,
    const float* __restrict__ Wv, const float* __restrict__ bv,
    u16* __restrict__ x){
  int gid = blockIdx.x * 256 + threadIdx.x;      // 13504 blocks = NN*32
  int n = gid >> 5, cc = (gid & 31) << 2;
  int g = n / NPG, loc = n - g * NPG;
  float a[4];
  if (loc == 0){
    const float* in = head + (size_t)g * 2;
    float i0 = in[0], i1 = in[1];
    #pragma unroll
    for (int t = 0; t < 4; ++t){ int c = cc + t; a[t] = bh[c] + i0 * Wh[c] + i1 * Wh[128 + c]; }
  } else if (loc <= NOBJ){
    const float* in = obj + ((size_t)g * NOBJ + (loc - 1)) * 2;
    float i0 = in[0], i1 = in[1];
    #pragma unroll
    for (int t = 0; t < 4; ++t){ int c = cc + t; a[t] = bo[c] + i0 * Wo[c] + i1 * Wo[128 + c]; }
  } else {
    const float* in = val + ((size_t)g * NVAL + (loc - 11)) * 5;
    float f[5];
    #pragma unroll
    for (int k = 0; k < 5; ++k) f[k] = in[k];
    #pragma unroll
    for (int t = 0; t < 4; ++t){
      int c = cc + t; float s = bv[c];
      #pragma unroll
      for (int k = 0; k < 5; ++k) s += f[k] * Wv[k * 128 + c];
      a[t] = s;
    }
  }
  ushort4 u;
  u.x = f2bf(fmaxf(a[0], 0.f)); u.y = f2bf(fmaxf(a[1], 0.f));
  u.z = f2bf(fmaxf(a[2], 0.f)); u.w = f2bf(fmaxf(a[3], 0.f));
  *(ushort4*)&x[(size_t)n * 128 + cc] = u;
}

// ---- CSR build: per-graph block ----
__global__ __launch_bounds__(256) void k_csr2(const int* __restrict__ eidx,
                                              int* __restrict__ coff, int* __restrict__ csrc){
  __shared__ int sEs[420], sEd[420], sTmp[256], sOff[212], sSrc[632];
  int g = blockIdx.x, tid = threadIdx.x;
  const int4* e4 = (const int4*)(eidx + (size_t)g * 840);
  for (int i = tid; i < 105; i += 256){ ((int4*)sEs)[i] = e4[i]; ((int4*)sEd)[i] = e4[105 + i]; }
  __syncthreads();
  int deg = 0;
  if (tid < NPG){
    deg = 1;
    const int4* p4 = (const int4*)sEd;
    #pragma unroll 4
    for (int i = 0; i < 105; ++i){
      int4 v = p4[i];
      deg += (v.x == tid) + (v.y == tid) + (v.z == tid) + (v.w == tid);
    }
  }
  int v = deg;
  #pragma unroll
  for (int st = 1; st < 256; st <<= 1){
    sTmp[tid] = v;
    __syncthreads();
    if (tid >= st) v += sTmp[tid - st];
    __syncthreads();
  }
  if (tid < NPG) sOff[tid] = v - deg;
  if (tid == NPG - 1) sOff[NPG] = v;
  __syncthreads();
  if (tid < NPG){
    int p = sOff[tid];
    sSrc[p++] = tid;                              // self loop first
    const int4* pd4 = (const int4*)sEd;
    const int4* ps4 = (const int4*)sEs;
    for (int i = 0; i < 105; ++i){
      int4 d = pd4[i]; int4 s = ps4[i];
      if (d.x == tid) sSrc[p++] = s.x;
      if (d.y == tid) sSrc[p++] = s.y;
      if (d.z == tid) sSrc[p++] = s.z;
      if (d.w == tid) sSrc[p++] = s.w;
    }
  }
  __syncthreads();
  if (tid < 212) coff[(size_t)g * 212 + tid] = sOff[tid];
  for (int i = tid; i < 631; i += 256) csrc[(size_t)g * 632 + i] = sSrc[i];
}

// ---- MFMA GEMM (R9-validated): C[Mx128] = sum_ch A @ Bt^T ----
template<int KCH, bool RELU>
__global__ __launch_bounds__(512) void k_mm(const u16* __restrict__ A, int aStride, int chunkOff,
                                            const u16* __restrict__ Bt, int bstride,
                                            const float* __restrict__ bias, u16* __restrict__ C){
  __shared__ u16 sA[128 * 128];
  __shared__ u16 sB[128 * 128];
  const int tid = threadIdx.x, lane = tid & 63, w = tid >> 6;
  const int l15 = lane & 15, lg = lane >> 4;
  const int row0 = blockIdx.x * 128;
  f32x4 acc[8];
  #pragma unroll
  for (int ni = 0; ni < 8; ++ni) acc[ni] = (f32x4){0,0,0,0};

  #pragma unroll 1
  for (int ch = 0; ch < KCH; ++ch){
    const u16* Ab = A + (size_t)ch * chunkOff;
    const u16* Bb = Bt + ch * 128;
    #pragma unroll
    for (int i = 0; i < 4; ++i){
      int r = w * 16 + i * 4 + (lane >> 4);
      int c16 = lane & 15;
      int sw = (c16 ^ (r & 15)) << 4;
      __builtin_amdgcn_global_load_lds(AS_GLOBAL((const char*)(Ab + (size_t)(row0 + r) * aStride) + sw),
                                       AS_LDS(&sA[(w * 16 + i * 4) * 128]), 16, 0, 0);
      __builtin_amdgcn_global_load_lds(AS_GLOBAL((const char*)(Bb + (size_t)r * bstride) + sw),
                                       AS_LDS(&sB[(w * 16 + i * 4) * 128]), 16, 0, 0);
    }
    __syncthreads();
    #pragma unroll
    for (int kk = 0; kk < 4; ++kk){
      int k0 = kk * 32 + lg * 4;
      int rr = w * 16 + l15;
      short8 af = pack8(*(const ushort4*)&sA[s16(rr, k0)],
                        *(const ushort4*)&sA[s16(rr, k0 + 16)]);
      #pragma unroll
      for (int ni = 0; ni < 8; ++ni){
        int cc = ni * 16 + l15;
        short8 bf = pack8(*(const ushort4*)&sB[s16(cc, k0)],
                          *(const ushort4*)&sB[s16(cc, k0 + 16)]);
        acc[ni] = __builtin_amdgcn_mfma_f32_16x16x32_bf16(af, bf, acc[ni], 0, 0, 0);
      }
    }
    __syncthreads();
  }
  const int r0 = row0 + w * 16 + lg * 4;
  #pragma unroll
  for (int ni = 0; ni < 8; ++ni){
    int col = ni * 16 + l15;
    float bv = RELU ? bias[col] : 0.f;
    #pragma unroll
    for (int r = 0; r < 4; ++r){
      float v = acc[ni][r];
      if (RELU) v = fmaxf(v + bv, 0.f);
      C[(size_t)(r0 + r) * 128 + col] = f2bf(v);
    }
  }
}

// ---- FUSED att1 + softmax-weights: one block per graph ----
__global__ __launch_bounds__(512) void k_attsm1(const u16* __restrict__ xs1,
                                                const float* __restrict__ as1, const float* __restrict__ ad1,
                                                const int* __restrict__ coff, const int* __restrict__ csrc,
                                                float* __restrict__ wn, float* __restrict__ rden){
  __shared__ float sLs[844], sLd[844];
  const int g = blockIdx.x, tid = threadIdx.x;
  const int gb = g * NPG;
  for (int t = tid; t < NPG * 4; t += 512){
    int n = t >> 2, h = t & 3;
    const u16* xr = xs1 + (size_t)(gb + n) * 128 + h * 32;
    float s = 0.f, d = 0.f;
    #pragma unroll
    for (int j = 0; j < 8; ++j){
      ushort4 xv = *(const ushort4*)(xr + j * 4);
      #pragma unroll
      for (int q = 0; q < 4; ++q){
        float xf = bf2f(((const u16*)&xv)[q]);
        int c = h * 32 + j * 4 + q;
        s += xf * as1[c];
        d += xf * ad1[c];
      }
    }
    sLs[t] = s; sLd[t] = d;
  }
  __syncthreads();
  for (int t = tid; t < NPG * 4; t += 512){
    int dst = t >> 2, h = t & 3;
    int o0 = coff[(size_t)g * 212 + dst], o1 = coff[(size_t)g * 212 + dst + 1];
    const int* sp = csrc + (size_t)g * 632;
    float ad = sLd[t];
    float m = -3e38f;
    for (int e = o0; e < o1; ++e) m = fmaxf(m, lrelu(sLs[sp[e] * 4 + h] + ad));
    float dn = 0.f;
    float* wp = wn + (size_t)g * 2528 + h * 632;
    for (int e = o0; e < o1; ++e){
      float ee = __expf(lrelu(sLs[sp[e] * 4 + h] + ad) - m);
      wp[e] = ee; dn += ee;
    }
    rden[(size_t)(gb + dst) * 4 + h] = 1.0f / (dn + 1e-16f);
  }
}

// ---- FUSED att2 + softmax-weights (fold=0.25) ----
__global__ __launch_bounds__(512) void k_attsm2(const u16* __restrict__ x1,
                                                const float* __restrict__ wms, const float* __restrict__ wmd,
                                                const int* __restrict__ coff, const int* __restrict__ csrc,
                                                float* __restrict__ wn, float* __restrict__ rden){
  __shared__ float sw[1024];
  __shared__ float sLs[844], sLd[844];
  const int g = blockIdx.x, tid = threadIdx.x;
  const int gb = g * NPG;
  for (int i = tid; i < 1024; i += 512) sw[i] = (i < 512) ? wms[i] : wmd[i - 512];
  __syncthreads();
  for (int t = tid; t < NPG * 4; t += 512){
    int n = t >> 2, h = t & 3;
    const u16* xr = x1 + (size_t)(gb + n) * 128;
    const float* wsp = sw + h * 128;
    const float* wdp = sw + 512 + h * 128;
    float s = 0.f, d = 0.f;
    #pragma unroll
    for (int j = 0; j < 32; ++j){
      ushort4 xv = *(const ushort4*)(xr + j * 4);
      #pragma unroll
      for (int q = 0; q < 4; ++q){
        float xf = bf2f(((const u16*)&xv)[q]);
        s += xf * wsp[j * 4 + q];
        d += xf * wdp[j * 4 + q];
      }
    }
    sLs[t] = s; sLd[t] = d;
  }
  __syncthreads();
  for (int t = tid; t < NPG * 4; t += 512){
    int dst = t >> 2, h = t & 3;
    int o0 = coff[(size_t)g * 212 + dst], o1 = coff[(size_t)g * 212 + dst + 1];
    const int* sp = csrc + (size_t)g * 632;
    float ad = sLd[t];
    float m = -3e38f;
    for (int e = o0; e < o1; ++e) m = fmaxf(m, lrelu(sLs[sp[e] * 4 + h] + ad));
    float dn = 0.f;
    float* wp = wn + (size_t)g * 2528 + h * 632;
    for (int e = o0; e < o1; ++e){
      float ee = __expf(lrelu(sLs[sp[e] * 4 + h] + ad) - m);
      wp[e] = ee; dn += ee;
    }
    rden[(size_t)(gb + dst) * 4 + h] = 0.25f / (dn + 1e-16f);
  }
}

// ---- gat1: wave per dst, thread per col-pair; x1 = relu(b1 + A~xs1) ----
__global__ __launch_bounds__(256) void k_gat1k(const u16* __restrict__ xs1,
                                               const float* __restrict__ wn, const float* __restrict__ rden,
                                               const int* __restrict__ coff, const int* __restrict__ csrc,
                                               const float* __restrict__ b1, u16* __restrict__ x1){
  int bid = blockIdx.x;                          // 512*53
  int g = bid / 53, ch = bid - g * 53;
  int dst = ch * 4 + (threadIdx.x >> 6);
  if (dst >= NPG) return;
  int lane = threadIdx.x & 63;
  int cp = lane << 1, hh = lane >> 4;
  int gb = g * NPG;
  int o0 = coff[(size_t)g * 212 + dst], o1 = coff[(size_t)g * 212 + dst + 1];
  const int* sp = csrc + (size_t)g * 632;
  const float* wp = wn + (size_t)g * 2528 + hh * 632;
  float a0 = 0.f, a1 = 0.f;
  for (int e = o0; e < o1; ++e){
    int src = sp[e];
    u32 f = *(const u32*)&xs1[(size_t)(gb + src) * 128 + cp];
    float w = wp[e];
    a0 += w * lo_bf(f); a1 += w * hi_bf(f);
  }
  float rv = rden[(size_t)(gb + dst) * 4 + hh];
  *(u32*)&x1[(size_t)(gb + dst) * 128 + cp] =
    pack_bf(fmaxf(a0 * rv + b1[cp], 0.f), fmaxf(a1 * rv + b1[cp + 1], 0.f));
}

// ---- FUSED gat2-aggregate + GEMM2 + final projections, row-block grid ----
// Block covers out rows [row0, row0+128). Per head h: aggregate y_h rows into
// sA (swz), stage W2t chunk h into sB (global_load_lds), MFMA accumulate.
// Epilogue: relu(acc+b2), in-register projections -> out. No y/z/out2 in HBM.
__global__ __launch_bounds__(512) void k_yagg(
    const u16* __restrict__ x1, const float* __restrict__ wn, const float* __restrict__ rden,
    const int* __restrict__ coff, const int* __restrict__ csrc,
    const u16* __restrict__ W2t, const float* __restrict__ b2,
    const float* __restrict__ amask,
    const float* __restrict__ Wacc, const float* __restrict__ bacc,
    const float* __restrict__ Woff, const float* __restrict__ boff,
    const float* __restrict__ Wvf,  const float* __restrict__ bvf,
    float* __restrict__ out)
{
  __shared__ u16 sA[128 * 128];
  __shared__ u16 sB[128 * 128];
  const int tid = threadIdx.x, lane = tid & 63, w = tid >> 6;
  const int l15 = lane & 15, lg = lane >> 4;
  const int cp = lane << 1;
  // bijective XCD chunk swizzle (844 = 4*106 + 4*105)
  const int xcd = blockIdx.x & 7, j = blockIdx.x >> 3;
  const int nb  = (xcd < 4 ? xcd * 106 : 4 * 106 + (xcd - 4) * 105) + j;
  const int row0 = nb * 128;

  f32x4 acc[8];
  #pragma unroll
  for (int ni = 0; ni < 8; ++ni) acc[ni] = (f32x4){0,0,0,0};

  #pragma unroll 1
  for (int h = 0; h < 4; ++h){
    // stage W2t chunk h -> sB (async; drained by the barrier below)
    #pragma unroll
    for (int i = 0; i < 4; ++i){
      int r = w * 16 + i * 4 + (lane >> 4);
      int c16 = lane & 15;
      int sw = (c16 ^ (r & 15)) << 4;
      __builtin_amdgcn_global_load_lds(AS_GLOBAL((const char*)(W2t + (size_t)r * 512 + h * 128) + sw),
                                       AS_LDS(&sB[(w * 16 + i * 4) * 128]), 16, 0, 0);
    }
    // aggregate y_h for this wave's 16 dst rows -> sA (swizzled u32 writes)
    for (int t = 0; t < 16; ++t){
      int row = row0 + w * 16 + t;
      int g = row / NPG, loc = row - g * NPG;
      int gb = g * NPG;
      int o0 = coff[(size_t)g * 212 + loc], o1 = coff[(size_t)g * 212 + loc + 1];
      const int* sp = csrc + (size_t)g * 632;
      const float* wp = wn + (size_t)g * 2528 + h * 632;
      float a0 = 0.f, a1 = 0.f;
      int e = o0;
      for (; e + 4 <= o1; e += 4){
        int s0 = sp[e], s1 = sp[e+1], s2 = sp[e+2], s3 = sp[e+3];
        u32 f0 = *(const u32*)&x1[(size_t)(gb + s0) * 128 + cp];
        u32 f1 = *(const u32*)&x1[(size_t)(gb + s1) * 128 + cp];
        u32 f2 = *(const u32*)&x1[(size_t)(gb + s2) * 128 + cp];
        u32 f3 = *(const u32*)&x1[(size_t)(gb + s3) * 128 + cp];
        float w0 = wp[e], w1 = wp[e+1], w2 = wp[e+2], w3 = wp[e+3];
        a0 += w0 * lo_bf(f0); a1 += w0 * hi_bf(f0);
        a0 += w1 * lo_bf(f1); a1 += w1 * hi_bf(f1);
        a0 += w2 * lo_bf(f2); a1 += w2 * hi_bf(f2);
        a0 += w3 * lo_bf(f3); a1 += w3 * hi_bf(f3);
      }
      for (; e < o1; ++e){
        int src = sp[e];
        u32 f = *(const u32*)&x1[(size_t)(gb + src) * 128 + cp];
        float wv = wp[e];
        a0 += wv * lo_bf(f); a1 += wv * hi_bf(f);
      }
      float rv = rden[(size_t)row * 4 + h];
      *(u32*)&sA[s16(w * 16 + t, cp)] = pack_bf(a0 * rv, a1 * rv);
    }
    __syncthreads();                               // drains gload_lds + sA writes
    // MFMA: acc += y_h @ W2_h^T
    #pragma unroll
    for (int kk = 0; kk < 4; ++kk){
      int k0 = kk * 32 + lg * 4;
      int rr = w * 16 + l15;
      short8 af = pack8(*(const ushort4*)&sA[s16(rr, k0)],
                        *(const ushort4*)&sA[s16(rr, k0 + 16)]);
      #pragma unroll
      for (int ni = 0; ni < 8; ++ni){
        int cc = ni * 16 + l15;
        short8 bf = pack8(*(const ushort4*)&sB[s16(cc, k0)],
                          *(const ushort4*)&sB[s16(cc, k0 + 16)]);
        acc[ni] = __builtin_amdgcn_mfma_f32_16x16x32_bf16(af, bf, acc[ni], 0, 0, 0);
      }
    }
    __syncthreads();
  }

  // ---- epilogue: out2 rows = relu(acc + b2); project in-register ----
  float bv[8];
  #pragma unroll
  for (int ni = 0; ni < 8; ++ni) bv[ni] = b2[ni * 16 + l15];
  #pragma unroll
  for (int r = 0; r < 4; ++r){
    int row = row0 + w * 16 + lg * 4 + r;
    int g = row / NPG, loc = row - g * NPG;
    float v[8];
    #pragma unroll
    for (int ni = 0; ni < 8; ++ni) v[ni] = fmaxf(acc[ni][r] + bv[ni], 0.f);
    if (loc == 0){
      float pA0 = 0.f, pA1 = 0.f, pV = 0.f;
      #pragma unroll
      for (int ni = 0; ni < 8; ++ni){
        int c = ni * 16 + l15;
        pA0 += v[ni] * Wacc[c * 2];
        pA1 += v[ni] * Wacc[c * 2 + 1];
        pV  += v[ni] * Wvf[c];
      }
      #pragma unroll
      for (int s = 1; s < 16; s <<= 1){
        pA0 += __shfl_xor(pA0, s);
        pA1 += __shfl_xor(pA1, s);
        pV  += __shfl_xor(pV, s);
      }
      if (l15 == 0){
        float lm0 = fmaxf(logf(amask[g * 2]),     -3.402823466e38f);
        float lm1 = fmaxf(logf(amask[g * 2 + 1]), -3.402823466e38f);
        out[(size_t)g * 203]       = pA0 + bacc[0] + lm0;
        out[(size_t)g * 203 + 1]   = pA1 + bacc[1] + lm1;
        out[(size_t)g * 203 + 202] = pV + bvf[0];
      }
    } else if (loc >= 11){
      float pO = 0.f;
      #pragma unroll
      for (int ni = 0; ni < 8; ++ni) pO += v[ni] * Woff[ni * 16 + l15];
      #pragma unroll
      for (int s = 1; s < 16; s <<= 1) pO += __shfl_xor(pO, s);
      if (l15 == 0) out[(size_t)g * 203 + 2 + (loc - 11)] = pO + boff[0];
    }
  }
}

extern "C" void kernel_launch(void* const* d_in, const int* in_sizes, int n_in,
                              void* d_out, int out_size, void* d_ws, size_t ws_size,
                              hipStream_t stream){
  (void)in_sizes; (void)n_in; (void)out_size; (void)ws_size;
  const float* head = (const float*)d_in[0];
  const float* obj  = (const float*)d_in[1];
  const float* val  = (const float*)d_in[2];
  const int*   eidx = (const int*)d_in[3];
  const float* amask= (const float*)d_in[4];
  const float* Wh   = (const float*)d_in[5];
  const float* bh   = (const float*)d_in[6];
  const float* Wo   = (const float*)d_in[7];
  const float* bo   = (const float*)d_in[8];
  const float* Wv   = (const float*)d_in[9];
  const float* bv   = (const float*)d_in[10];
  const float* W1   = (const float*)d_in[11];
  const float* as1  = (const float*)d_in[12];
  const float* ad1  = (const float*)d_in[13];
  const float* b1   = (const float*)d_in[14];
  const float* W2   = (const float*)d_in[15];
  const float* as2  = (const float*)d_in[16];
  const float* ad2  = (const float*)d_in[17];
  const float* b2   = (const float*)d_in[18];
  const float* Wacc = (const float*)d_in[19];
  const float* bacc = (const float*)d_in[20];
  const float* Woff = (const float*)d_in[21];
  const float* boff = (const float*)d_in[22];
  const float* Wvf  = (const float*)d_in[23];
  const float* bvf  = (const float*)d_in[24];
  float* out = (float*)d_out;

  char* ws = (char*)d_ws;
  u16*   W1t = (u16*)ws;                     // @0,        32768
  u16*   W2t = (u16*)(ws + 32768);           // @32768,   131072
  float* wms = (float*)(ws + 163840);        // @163840,    2048
  float* wmd = (float*)(ws + 165888);        // @165888,    2048
  int*   coff = (int*)(ws + 167936);         //   434176 -> ends   602112
  int*   csrc = (int*)(ws + 602112);         //  1294336 -> ends  1896448
  float* wn   = (float*)(ws + 5353472);      //  5177344 -> ends 10530816
  float* rden = (float*)(ws + 10530816);     //  1728512 -> ends 12259328
  u16*   x    = (u16*)(ws + 12259328);       // 27656192 -> ends 39915520  (x, then x1)
  u16*   xs1  = (u16*)(ws + 39915520);       // 27656192 -> ends 67571712

  k_prep<<<324, 256, 0, stream>>>(W1, W2, as2, ad2, W1t, W2t, wms, wmd);
  k_embed2<<<NN * 32 / 256, 256, 0, stream>>>(head, obj, val, Wh, bh, Wo, bo, Wv, bv, x);
  k_csr2<<<NB, 256, 0, stream>>>(eidx, coff, csrc);
  k_mm<1, false><<<NN / 128, 512, 0, stream>>>(x, 128, 0, W1t, 128, nullptr, xs1);
  k_attsm1<<<NB, 512, 0, stream>>>(xs1, as1, ad1, coff, csrc, wn, rden);
  k_gat1k<<<NB * 53, 256, 0, stream>>>(xs1, wn, rden, coff, csrc, b1, x);   // x := x1
  k_attsm2<<<NB, 512, 0, stream>>>(x, wms, wmd, coff, csrc, wn, rden);
  k_yagg<<<NN / 128, 512, 0, stream>>>(x, wn, rden, coff, csrc, W2t, b2, amask,
                                       Wacc, bacc, Woff, boff, Wvf, bvf, out);
}